// Round 1
// 1582.305 us; speedup vs baseline: 1.3185x; 1.3185x over previous
//
#include <hip/hip_runtime.h>
#include <stdint.h>

constexpr int Bc = 4096;
constexpr int Kc = 32;
constexpr int Dc = 1024;
constexpr int Rc = 128;
constexpr int MNB = Bc * Kc;          // 131072 neighbor rows

typedef __attribute__((ext_vector_type(8))) short short8;
typedef __attribute__((ext_vector_type(4))) float floatx4;

__device__ __forceinline__ unsigned short f2bf(float x) {
  union { float f; uint32_t u; } v; v.f = x;
  return (unsigned short)((v.u + 0x7fffu + ((v.u >> 16) & 1u)) >> 16);
}
__device__ __forceinline__ float bf2f(unsigned short b) {
  union { float f; uint32_t u; } v; v.u = ((uint32_t)b) << 16;
  return v.f;
}

__device__ __forceinline__ void async_copy16(const void* g, void* l) {
  __builtin_amdgcn_global_load_lds(
      (const __attribute__((address_space(1))) void*)g,
      (__attribute__((address_space(3))) void*)l, 16, 0, 0);
}

// ---------------------------------------------------------------------------
// K1: fused LayerNorm of target (rows 0..4095) and neighbors -> bf16
// one block per row of 1024
// ---------------------------------------------------------------------------
__global__ __launch_bounds__(256) void ln_kernel(
    const float* __restrict__ target, const float* __restrict__ neighbors,
    const float* __restrict__ scale, const float* __restrict__ bias,
    unsigned short* __restrict__ tc_bf, unsigned short* __restrict__ nb_bf) {
  int row = blockIdx.x;
  const float* src;
  unsigned short* dst;
  if (row < Bc) {
    src = target + (size_t)row * Dc;
    dst = tc_bf + (size_t)row * Dc;
  } else {
    size_t r2 = (size_t)(row - Bc);
    src = neighbors + r2 * Dc;
    dst = nb_bf + r2 * Dc;
  }
  int t = threadIdx.x;
  float4 x = ((const float4*)src)[t];
  float s = x.x + x.y + x.z + x.w;
  float ss = x.x * x.x + x.y * x.y + x.z * x.z + x.w * x.w;
#pragma unroll
  for (int m = 32; m >= 1; m >>= 1) {
    s += __shfl_xor(s, m, 64);
    ss += __shfl_xor(ss, m, 64);
  }
  __shared__ float red[8];
  int wave = t >> 6, lane = t & 63;
  if (lane == 0) { red[wave] = s; red[wave + 4] = ss; }
  __syncthreads();
  s = red[0] + red[1] + red[2] + red[3];
  ss = red[4] + red[5] + red[6] + red[7];
  float mu = s * (1.0f / Dc);
  float var = ss * (1.0f / Dc) - mu * mu;
  float rstd = rsqrtf(var + 1e-5f);
  float4 sc = ((const float4*)scale)[t];
  float4 bi = ((const float4*)bias)[t];
  ushort4 o;
  o.x = f2bf((x.x - mu) * rstd * sc.x + bi.x);
  o.y = f2bf((x.y - mu) * rstd * sc.y + bi.y);
  o.z = f2bf((x.z - mu) * rstd * sc.z + bi.z);
  o.w = f2bf((x.w - mu) * rstd * sc.w + bi.w);
  ((ushort4*)dst)[t] = o;
}

// ---------------------------------------------------------------------------
// K2: f32 -> bf16 converter (for weight matrices)
// ---------------------------------------------------------------------------
__global__ __launch_bounds__(256) void conv_kernel(
    const float* __restrict__ src, unsigned short* __restrict__ dst, int n4) {
  int i = blockIdx.x * 256 + threadIdx.x;
  if (i < n4) {
    float4 x = ((const float4*)src)[i];
    ushort4 o;
    o.x = f2bf(x.x); o.y = f2bf(x.y); o.z = f2bf(x.z); o.w = f2bf(x.w);
    ((ushort4*)dst)[i] = o;
  }
}

// ---------------------------------------------------------------------------
// GEMM: C[m,n] = sum_k A[m,k] * B[n,k] + bias[n]   (NT, both row-major, ld=Kd)
// bf16 inputs, f32 out. 128x128 tile, BK=64, 256 threads (4 waves 2x2),
// each wave 4x4 grid of 16x16x32 MFMAs. global_load_lds width-16 staging.
// EPI: 0 = plain +bias, 1 = +bias then leaky_relu(0.01)
// ---------------------------------------------------------------------------
template <int EPI>
__global__ __launch_bounds__(256) void gemm_bf16(
    const unsigned short* __restrict__ A, const unsigned short* __restrict__ Bm,
    const float* __restrict__ bias, float* __restrict__ C,
    int M, int N, int Kd, int NN, int NMdiv8) {
  __shared__ short Alds[128 * 64];
  __shared__ short Blds[128 * 64];

  // XCD-aware swizzle: each XCD gets a contiguous M-slab, bn iterates fastest
  int g = blockIdx.x;
  int xcd = g & 7;
  int t = g >> 3;
  int bn = t % NN;
  int bm = xcd * NMdiv8 + t / NN;

  int tid = threadIdx.x;
  int wave = tid >> 6;
  int lane = tid & 63;
  int wm = (wave >> 1) * 64;
  int wn = (wave & 1) * 64;

  floatx4 acc[4][4];
#pragma unroll
  for (int mi = 0; mi < 4; ++mi)
#pragma unroll
    for (int ni = 0; ni < 4; ++ni) {
      floatx4 z = {0.f, 0.f, 0.f, 0.f};
      acc[mi][ni] = z;
    }

  int srow = lane >> 3;          // 0..7 row within an 8-row staging group
  int scol = (lane & 7) * 8;     // element col within BK=64
  size_t lda = (size_t)Kd;

  for (int k0 = 0; k0 < Kd; k0 += 64) {
#pragma unroll
    for (int i = 0; i < 4; ++i) {
      int grp = wave * 4 + i;                 // 0..15, 8 rows each
      int rA = grp * 8 + srow;                // 0..127 within tile
      const unsigned short* gA = A + ((size_t)(bm * 128 + rA)) * lda + k0 + scol;
      const unsigned short* gB = Bm + ((size_t)(bn * 128 + rA)) * lda + k0 + scol;
      async_copy16(gA, &Alds[grp * 512]);
      async_copy16(gB, &Blds[grp * 512]);
    }
    __syncthreads();
#pragma unroll
    for (int ks = 0; ks < 2; ++ks) {
      short8 af[4], bf[4];
#pragma unroll
      for (int mi = 0; mi < 4; ++mi)
        af[mi] = *(const short8*)&Alds[(wm + mi * 16 + (lane & 15)) * 64 +
                                       ks * 32 + (lane >> 4) * 8];
#pragma unroll
      for (int ni = 0; ni < 4; ++ni)
        bf[ni] = *(const short8*)&Blds[(wn + ni * 16 + (lane & 15)) * 64 +
                                       ks * 32 + (lane >> 4) * 8];
#pragma unroll
      for (int mi = 0; mi < 4; ++mi)
#pragma unroll
        for (int ni = 0; ni < 4; ++ni)
          acc[mi][ni] = __builtin_amdgcn_mfma_f32_16x16x32_bf16(
              af[mi], bf[ni], acc[mi][ni], 0, 0, 0);
    }
    __syncthreads();
  }

  // epilogue: C/D layout col=lane&15, row=(lane>>4)*4+r
  int quad = lane >> 4;
  int col15 = lane & 15;
#pragma unroll
  for (int mi = 0; mi < 4; ++mi) {
#pragma unroll
    for (int ni = 0; ni < 4; ++ni) {
      int n_g = bn * 128 + wn + ni * 16 + col15;
      float bv = bias[n_g];
#pragma unroll
      for (int r = 0; r < 4; ++r) {
        int m_g = bm * 128 + wm + mi * 16 + quad * 4 + r;
        float v = acc[mi][ni][r] + bv;
        if (EPI == 1) v = (v > 0.f) ? v : 0.01f * v;
        C[(size_t)m_g * N + n_g] = v;
      }
    }
  }
}

// ---------------------------------------------------------------------------
// Fused neighbor-score GEMM + softmax(33) + threshold + context accumulation.
// A = nb_bf (MNB x Dc), Bm = wnb_bf (Dc x Dc), bias = b_nb.
// A 128-row tile = 4 complete b-groups (32 k each). Within a wave the 32
// k-scores of a fixed (b, n) live across the 4 quad lanes {c, c+16, c+32,
// c+48} (8 acc values each) -> shfl_xor(16/32) gives max/sum over k.
// Writes: nbw weights (in nbw region), selfw weights in place over the
// self-score buffer, ctx_bf for the reduction GEMM.
// ---------------------------------------------------------------------------
__global__ __launch_bounds__(256) void gemm_nb_fused(
    const unsigned short* __restrict__ A, const unsigned short* __restrict__ Bm,
    const float* __restrict__ bias, const float* __restrict__ distances,
    const float* __restrict__ beta_p, const unsigned short* __restrict__ tc_bf,
    float* __restrict__ selfsc, float* __restrict__ nbw,
    unsigned short* __restrict__ ctx_bf) {
  __shared__ short Alds[128 * 64];
  __shared__ short Blds[128 * 64];
  __shared__ float dw_lds[128];          // dist weights for 4 b's x 32 k

  constexpr int NN = 8;                  // 1024/128 col tiles
  constexpr int NMdiv8 = 128;            // (131072/128)/8 row tiles per XCD
  int g = blockIdx.x;
  int xcd = g & 7;
  int t = g >> 3;
  int bn = t % NN;
  int bm = xcd * NMdiv8 + t / NN;
  int b0 = bm * 4;                       // first of 4 b-groups in this tile

  int tid = threadIdx.x;
  int wave = tid >> 6;
  int lane = tid & 63;
  int wm = (wave >> 1) * 64;
  int wn = (wave & 1) * 64;

  if (tid < 128) {
    int b_loc = tid >> 5, k = tid & 31;
    dw_lds[tid] = __expf((float)(-2.0 / 100.00000001) *
                         distances[(size_t)(b0 + b_loc) * Kc + k]);
  }

  floatx4 acc[4][4];
#pragma unroll
  for (int mi = 0; mi < 4; ++mi)
#pragma unroll
    for (int ni = 0; ni < 4; ++ni) {
      floatx4 z = {0.f, 0.f, 0.f, 0.f};
      acc[mi][ni] = z;
    }

  int srow = lane >> 3;
  int scol = (lane & 7) * 8;
  size_t lda = (size_t)Dc;

  for (int k0 = 0; k0 < Dc; k0 += 64) {
#pragma unroll
    for (int i = 0; i < 4; ++i) {
      int grp = wave * 4 + i;
      int rA = grp * 8 + srow;
      const unsigned short* gA = A + ((size_t)(bm * 128 + rA)) * lda + k0 + scol;
      const unsigned short* gB = Bm + ((size_t)(bn * 128 + rA)) * lda + k0 + scol;
      async_copy16(gA, &Alds[grp * 512]);
      async_copy16(gB, &Blds[grp * 512]);
    }
    __syncthreads();
#pragma unroll
    for (int ks = 0; ks < 2; ++ks) {
      short8 af[4], bf[4];
#pragma unroll
      for (int mi = 0; mi < 4; ++mi)
        af[mi] = *(const short8*)&Alds[(wm + mi * 16 + (lane & 15)) * 64 +
                                       ks * 32 + (lane >> 4) * 8];
#pragma unroll
      for (int ni = 0; ni < 4; ++ni)
        bf[ni] = *(const short8*)&Blds[(wn + ni * 16 + (lane & 15)) * 64 +
                                       ks * 32 + (lane >> 4) * 8];
#pragma unroll
      for (int mi = 0; mi < 4; ++mi)
#pragma unroll
        for (int ni = 0; ni < 4; ++ni)
          acc[mi][ni] = __builtin_amdgcn_mfma_f32_16x16x32_bf16(
              af[mi], bf[ni], acc[mi][ni], 0, 0, 0);
    }
    __syncthreads();
  }

  // ---- fused epilogue -----------------------------------------------------
  // acc row layout: local row = wm + mi*16 + quad*4 + r
  //   b_local = (wave>>1)*2 + bh   (bh = mi>>1),  k = (mi&1)*16 + quad*4 + r
  int quad = lane >> 4;
  int col15 = lane & 15;
  float beta = beta_p[0];
  float omb = 1.0f - beta;

#pragma unroll
  for (int ni = 0; ni < 4; ++ni) {
    int n_g = bn * 128 + wn + ni * 16 + col15;
    float bv = bias[n_g];
#pragma unroll
    for (int bh = 0; bh < 2; ++bh) {
      int b_loc = (wave >> 1) * 2 + bh;        // 0..3 within tile
      int b = b0 + b_loc;
      size_t bd = (size_t)b * Dc + n_g;

      float l[8];
      float mx = -1e30f;
#pragma unroll
      for (int mo = 0; mo < 2; ++mo)
#pragma unroll
        for (int r = 0; r < 4; ++r) {
          int k = mo * 16 + quad * 4 + r;
          float v = (acc[bh * 2 + mo][ni][r] + bv) * dw_lds[b_loc * 32 + k];
          l[mo * 4 + r] = v;
          mx = fmaxf(mx, v);
        }
      mx = fmaxf(mx, __shfl_xor(mx, 16, 64));
      mx = fmaxf(mx, __shfl_xor(mx, 32, 64));
      float l0 = selfsc[bd];                   // self score (incl. bias)
      mx = fmaxf(mx, l0);

      float sum = 0.f;
#pragma unroll
      for (int i = 0; i < 8; ++i) {
        l[i] = __expf(l[i] - mx);
        sum += l[i];
      }
      sum += __shfl_xor(sum, 16, 64);
      sum += __shfl_xor(sum, 32, 64);
      float e0 = __expf(l0 - mx);
      float inv = 1.0f / (sum + e0);

      float w0 = e0 * inv;
      if (w0 < 0.01f) w0 = 0.f;

      float ctxn = 0.f;
#pragma unroll
      for (int mo = 0; mo < 2; ++mo)
#pragma unroll
        for (int r = 0; r < 4; ++r) {
          int k = mo * 16 + quad * 4 + r;
          float w = l[mo * 4 + r] * inv;
          if (w < 0.01f) w = 0.f;
          size_t idx = ((size_t)(b * Kc + k)) * Dc + n_g;
          nbw[idx] = w;
          ctxn += w * bf2f(A[idx]);            // nb_bf value at (b,k,n)
        }
      ctxn += __shfl_xor(ctxn, 16, 64);
      ctxn += __shfl_xor(ctxn, 32, 64);

      if (quad == 0) {
        selfsc[bd] = w0;                       // score -> weight, in place
        float ctx = beta * w0 * bf2f(tc_bf[bd]) + omb * ctxn;
        ctx_bf[bd] = f2bf(ctx);
      }
    }
  }
}

// ---------------------------------------------------------------------------
extern "C" void kernel_launch(void* const* d_in, const int* in_sizes, int n_in,
                              void* d_out, int out_size, void* d_ws,
                              size_t ws_size, hipStream_t stream) {
  const float* target    = (const float*)d_in[0];
  const float* neighbors = (const float*)d_in[1];
  const float* distances = (const float*)d_in[2];
  const float* beta      = (const float*)d_in[3];
  const float* ln_scale  = (const float*)d_in[4];
  const float* ln_bias   = (const float*)d_in[5];
  const float* w_self    = (const float*)d_in[6];
  const float* b_self    = (const float*)d_in[7];
  const float* w_nb      = (const float*)d_in[8];
  const float* b_nb      = (const float*)d_in[9];
  const float* w_red     = (const float*)d_in[10];
  const float* b_red     = (const float*)d_in[11];

  float* out = (float*)d_out;
  float* reduced = out;                          // 4096*128
  float* selfw   = out + (size_t)Bc * Rc;        // 4096*1024 (scores then weights)
  float* nbw     = selfw + (size_t)Bc * Dc;      // 131072*1024 (weights)

  char* ws = (char*)d_ws;
  unsigned short* nb_bf   = (unsigned short*)ws;                      // 268435456 B
  unsigned short* tc_bf   = (unsigned short*)(ws + 268435456);        // 8388608 B
  unsigned short* ctx_bf  = (unsigned short*)(ws + 276824064);        // 8388608 B
  unsigned short* wself_bf = (unsigned short*)(ws + 285212672);       // 2097152 B
  unsigned short* wnb_bf   = (unsigned short*)(ws + 287309824);       // 2097152 B
  unsigned short* wred_bf  = (unsigned short*)(ws + 289406976);       // 262144 B

  // 1. LayerNorm target + neighbors -> bf16
  ln_kernel<<<Bc + MNB, 256, 0, stream>>>(target, neighbors, ln_scale, ln_bias,
                                          tc_bf, nb_bf);
  // 2. weight conversions
  conv_kernel<<<1024, 256, 0, stream>>>(w_self, wself_bf, 262144);
  conv_kernel<<<1024, 256, 0, stream>>>(w_nb, wnb_bf, 262144);
  conv_kernel<<<128, 256, 0, stream>>>(w_red, wred_bf, 32768);
  // 3. self scores: (4096x1024) @ (1024x1024)^T -> selfw region (scores)
  gemm_bf16<0><<<256, 256, 0, stream>>>(tc_bf, wself_bf, b_self, selfw,
                                        Bc, Dc, Dc, 8, 4);
  // 4. fused: neighbor scores GEMM + softmax + threshold + context
  gemm_nb_fused<<<8192, 256, 0, stream>>>(nb_bf, wnb_bf, b_nb, distances, beta,
                                          tc_bf, selfw, nbw, ctx_bf);
  // 5. reduced: (4096x1024) @ (128x1024)^T + bias, leaky -> reduced region
  gemm_bf16<1><<<32, 256, 0, stream>>>(ctx_bf, wred_bf, b_red, reduced,
                                       Bc, Rc, Dc, 1, 4);
}

// Round 2
// 1543.419 us; speedup vs baseline: 1.3517x; 1.0252x over previous
//
#include <hip/hip_runtime.h>
#include <stdint.h>

constexpr int Bc = 4096;
constexpr int Kc = 32;
constexpr int Dc = 1024;
constexpr int Rc = 128;
constexpr int MNB = Bc * Kc;          // 131072 neighbor rows

typedef __attribute__((ext_vector_type(8))) short short8;
typedef __attribute__((ext_vector_type(4))) float floatx4;

__device__ __forceinline__ unsigned short f2bf(float x) {
  union { float f; uint32_t u; } v; v.f = x;
  return (unsigned short)((v.u + 0x7fffu + ((v.u >> 16) & 1u)) >> 16);
}
__device__ __forceinline__ float bf2f(unsigned short b) {
  union { float f; uint32_t u; } v; v.u = ((uint32_t)b) << 16;
  return v.f;
}

__device__ __forceinline__ void async_copy16(const void* g, void* l) {
  __builtin_amdgcn_global_load_lds(
      (const __attribute__((address_space(1))) void*)g,
      (__attribute__((address_space(3))) void*)l, 16, 0, 0);
}

// Stage one 128x64 A-tile + B-tile into LDS (linear dest, global source
// pre-swizzled so that global 16B-block j of row r lands at LDS block
// j ^ (r&7)).  scol must be ((lane&7) ^ srow) * 8.
__device__ __forceinline__ void stage_tile(
    const unsigned short* __restrict__ A, const unsigned short* __restrict__ Bm,
    short* Al, short* Bl, int bmBase, int bnBase, size_t lda, int k0,
    int wave, int srow, int scol) {
#pragma unroll
  for (int i = 0; i < 4; ++i) {
    int grp = wave * 4 + i;                 // 0..15, 8 rows each
    int rA = grp * 8 + srow;                // 0..127 within tile
    const unsigned short* gA = A + ((size_t)(bmBase + rA)) * lda + k0 + scol;
    const unsigned short* gB = Bm + ((size_t)(bnBase + rA)) * lda + k0 + scol;
    async_copy16(gA, &Al[grp * 512]);
    async_copy16(gB, &Bl[grp * 512]);
  }
}

// ---------------------------------------------------------------------------
// K1: fused LayerNorm of target (rows 0..4095) and neighbors -> bf16
// ---------------------------------------------------------------------------
__global__ __launch_bounds__(256) void ln_kernel(
    const float* __restrict__ target, const float* __restrict__ neighbors,
    const float* __restrict__ scale, const float* __restrict__ bias,
    unsigned short* __restrict__ tc_bf, unsigned short* __restrict__ nb_bf) {
  int row = blockIdx.x;
  const float* src;
  unsigned short* dst;
  if (row < Bc) {
    src = target + (size_t)row * Dc;
    dst = tc_bf + (size_t)row * Dc;
  } else {
    size_t r2 = (size_t)(row - Bc);
    src = neighbors + r2 * Dc;
    dst = nb_bf + r2 * Dc;
  }
  int t = threadIdx.x;
  float4 x = ((const float4*)src)[t];
  float s = x.x + x.y + x.z + x.w;
  float ss = x.x * x.x + x.y * x.y + x.z * x.z + x.w * x.w;
#pragma unroll
  for (int m = 32; m >= 1; m >>= 1) {
    s += __shfl_xor(s, m, 64);
    ss += __shfl_xor(ss, m, 64);
  }
  __shared__ float red[8];
  int wave = t >> 6, lane = t & 63;
  if (lane == 0) { red[wave] = s; red[wave + 4] = ss; }
  __syncthreads();
  s = red[0] + red[1] + red[2] + red[3];
  ss = red[4] + red[5] + red[6] + red[7];
  float mu = s * (1.0f / Dc);
  float var = ss * (1.0f / Dc) - mu * mu;
  float rstd = rsqrtf(var + 1e-5f);
  float4 sc = ((const float4*)scale)[t];
  float4 bi = ((const float4*)bias)[t];
  ushort4 o;
  o.x = f2bf((x.x - mu) * rstd * sc.x + bi.x);
  o.y = f2bf((x.y - mu) * rstd * sc.y + bi.y);
  o.z = f2bf((x.z - mu) * rstd * sc.z + bi.z);
  o.w = f2bf((x.w - mu) * rstd * sc.w + bi.w);
  ((ushort4*)dst)[t] = o;
}

// ---------------------------------------------------------------------------
// K2: f32 -> bf16 converter (for weight matrices)
// ---------------------------------------------------------------------------
__global__ __launch_bounds__(256) void conv_kernel(
    const float* __restrict__ src, unsigned short* __restrict__ dst, int n4) {
  int i = blockIdx.x * 256 + threadIdx.x;
  if (i < n4) {
    float4 x = ((const float4*)src)[i];
    ushort4 o;
    o.x = f2bf(x.x); o.y = f2bf(x.y); o.z = f2bf(x.z); o.w = f2bf(x.w);
    ((ushort4*)dst)[i] = o;
  }
}

// ---------------------------------------------------------------------------
// GEMM: C[m,n] = sum_k A[m,k] * B[n,k] + bias[n]   (NT, both row-major, ld=Kd)
// bf16 in, f32 out. 128x128 tile, BK=64, 256 threads (4 waves 2x2).
// Double-buffered LDS (one barrier per K-step), XOR-swizzled LDS layout
// (swizzled global source + swizzled ds_read -> conflict-free b128 reads).
// EPI: 0 = plain +bias, 1 = +bias then leaky_relu(0.01)
// ---------------------------------------------------------------------------
template <int EPI>
__global__ __launch_bounds__(256) void gemm_bf16(
    const unsigned short* __restrict__ A, const unsigned short* __restrict__ Bm,
    const float* __restrict__ bias, float* __restrict__ C,
    int M, int N, int Kd, int NN, int NMdiv8) {
  __shared__ short Alds[2][128 * 64];
  __shared__ short Blds[2][128 * 64];

  int g = blockIdx.x;
  int xcd = g & 7;
  int t = g >> 3;
  int bn = t % NN;
  int bm = xcd * NMdiv8 + t / NN;

  int tid = threadIdx.x;
  int wave = tid >> 6;
  int lane = tid & 63;
  int wm = (wave >> 1) * 64;
  int wn = (wave & 1) * 64;
  int quad = lane >> 4;
  int l15 = lane & 15;
  int x7 = lane & 7;

  floatx4 acc[4][4];
#pragma unroll
  for (int mi = 0; mi < 4; ++mi)
#pragma unroll
    for (int ni = 0; ni < 4; ++ni) {
      floatx4 z = {0.f, 0.f, 0.f, 0.f};
      acc[mi][ni] = z;
    }

  int srow = lane >> 3;                      // 0..7
  int scol = ((lane & 7) ^ srow) * 8;        // swizzled source col (elements)
  size_t lda = (size_t)Kd;
  int NT = Kd >> 6;

  stage_tile(A, Bm, Alds[0], Blds[0], bm * 128, bn * 128, lda, 0, wave, srow, scol);
  __syncthreads();

  for (int tk = 0; tk < NT; ++tk) {
    int cur = tk & 1;
    if (tk + 1 < NT)
      stage_tile(A, Bm, Alds[cur ^ 1], Blds[cur ^ 1], bm * 128, bn * 128, lda,
                 (tk + 1) * 64, wave, srow, scol);
    const short* Ab = Alds[cur];
    const short* Bb = Blds[cur];
#pragma unroll
    for (int ks = 0; ks < 2; ++ks) {
      short8 af[4], bfr[4];
#pragma unroll
      for (int mi = 0; mi < 4; ++mi)
        af[mi] = *(const short8*)&Ab[(wm + mi * 16 + l15) * 64 +
                                     (((ks * 4 + quad) ^ x7) << 3)];
#pragma unroll
      for (int ni = 0; ni < 4; ++ni)
        bfr[ni] = *(const short8*)&Bb[(wn + ni * 16 + l15) * 64 +
                                      (((ks * 4 + quad) ^ x7) << 3)];
#pragma unroll
      for (int mi = 0; mi < 4; ++mi)
#pragma unroll
        for (int ni = 0; ni < 4; ++ni)
          acc[mi][ni] = __builtin_amdgcn_mfma_f32_16x16x32_bf16(
              af[mi], bfr[ni], acc[mi][ni], 0, 0, 0);
    }
    __syncthreads();
  }

  // epilogue: C/D layout col=lane&15, row=(lane>>4)*4+r
  int col15 = lane & 15;
#pragma unroll
  for (int mi = 0; mi < 4; ++mi) {
#pragma unroll
    for (int ni = 0; ni < 4; ++ni) {
      int n_g = bn * 128 + wn + ni * 16 + col15;
      float bv = bias[n_g];
#pragma unroll
      for (int r = 0; r < 4; ++r) {
        int m_g = bm * 128 + wm + mi * 16 + quad * 4 + r;
        float v = acc[mi][ni][r] + bv;
        if (EPI == 1) v = (v > 0.f) ? v : 0.01f * v;
        C[(size_t)m_g * N + n_g] = v;
      }
    }
  }
}

// ---------------------------------------------------------------------------
// Fused neighbor-score GEMM + softmax(33) + threshold + context accumulation.
// Same dbuf + swizzle K-loop as gemm_bf16; epilogue unchanged from r1.
// ---------------------------------------------------------------------------
__global__ __launch_bounds__(256) void gemm_nb_fused(
    const unsigned short* __restrict__ A, const unsigned short* __restrict__ Bm,
    const float* __restrict__ bias, const float* __restrict__ distances,
    const float* __restrict__ beta_p, const unsigned short* __restrict__ tc_bf,
    float* __restrict__ selfsc, float* __restrict__ nbw,
    unsigned short* __restrict__ ctx_bf) {
  __shared__ short Alds[2][128 * 64];
  __shared__ short Blds[2][128 * 64];
  __shared__ float dw_lds[128];          // dist weights for 4 b's x 32 k

  constexpr int NN = 8;                  // 1024/128 col tiles
  constexpr int NMdiv8 = 128;            // (131072/128)/8 row tiles per XCD
  int g = blockIdx.x;
  int xcd = g & 7;
  int t = g >> 3;
  int bn = t % NN;
  int bm = xcd * NMdiv8 + t / NN;
  int b0 = bm * 4;                       // first of 4 b-groups in this tile

  int tid = threadIdx.x;
  int wave = tid >> 6;
  int lane = tid & 63;
  int wm = (wave >> 1) * 64;
  int wn = (wave & 1) * 64;
  int quad = lane >> 4;
  int l15 = lane & 15;
  int x7 = lane & 7;

  if (tid < 128) {
    int b_loc = tid >> 5, k = tid & 31;
    dw_lds[tid] = __expf((float)(-2.0 / 100.00000001) *
                         distances[(size_t)(b0 + b_loc) * Kc + k]);
  }

  floatx4 acc[4][4];
#pragma unroll
  for (int mi = 0; mi < 4; ++mi)
#pragma unroll
    for (int ni = 0; ni < 4; ++ni) {
      floatx4 z = {0.f, 0.f, 0.f, 0.f};
      acc[mi][ni] = z;
    }

  int srow = lane >> 3;
  int scol = ((lane & 7) ^ srow) * 8;
  size_t lda = (size_t)Dc;
  constexpr int NT = Dc >> 6;            // 16

  stage_tile(A, Bm, Alds[0], Blds[0], bm * 128, bn * 128, lda, 0, wave, srow, scol);
  __syncthreads();

  for (int tk = 0; tk < NT; ++tk) {
    int cur = tk & 1;
    if (tk + 1 < NT)
      stage_tile(A, Bm, Alds[cur ^ 1], Blds[cur ^ 1], bm * 128, bn * 128, lda,
                 (tk + 1) * 64, wave, srow, scol);
    const short* Ab = Alds[cur];
    const short* Bb = Blds[cur];
#pragma unroll
    for (int ks = 0; ks < 2; ++ks) {
      short8 af[4], bfr[4];
#pragma unroll
      for (int mi = 0; mi < 4; ++mi)
        af[mi] = *(const short8*)&Ab[(wm + mi * 16 + l15) * 64 +
                                     (((ks * 4 + quad) ^ x7) << 3)];
#pragma unroll
      for (int ni = 0; ni < 4; ++ni)
        bfr[ni] = *(const short8*)&Bb[(wn + ni * 16 + l15) * 64 +
                                      (((ks * 4 + quad) ^ x7) << 3)];
#pragma unroll
      for (int mi = 0; mi < 4; ++mi)
#pragma unroll
        for (int ni = 0; ni < 4; ++ni)
          acc[mi][ni] = __builtin_amdgcn_mfma_f32_16x16x32_bf16(
              af[mi], bfr[ni], acc[mi][ni], 0, 0, 0);
    }
    __syncthreads();
  }

  // ---- fused epilogue -----------------------------------------------------
  // acc row layout: local row = wm + mi*16 + quad*4 + r
  //   b_local = (wave>>1)*2 + bh   (bh = mi>>1),  k = (mi&1)*16 + quad*4 + r
  int col15 = lane & 15;
  float beta = beta_p[0];
  float omb = 1.0f - beta;

#pragma unroll
  for (int ni = 0; ni < 4; ++ni) {
    int n_g = bn * 128 + wn + ni * 16 + col15;
    float bv = bias[n_g];
#pragma unroll
    for (int bh = 0; bh < 2; ++bh) {
      int b_loc = (wave >> 1) * 2 + bh;        // 0..3 within tile
      int b = b0 + b_loc;
      size_t bd = (size_t)b * Dc + n_g;

      float l[8];
      float mx = -1e30f;
#pragma unroll
      for (int mo = 0; mo < 2; ++mo)
#pragma unroll
        for (int r = 0; r < 4; ++r) {
          int k = mo * 16 + quad * 4 + r;
          float v = (acc[bh * 2 + mo][ni][r] + bv) * dw_lds[b_loc * 32 + k];
          l[mo * 4 + r] = v;
          mx = fmaxf(mx, v);
        }
      mx = fmaxf(mx, __shfl_xor(mx, 16, 64));
      mx = fmaxf(mx, __shfl_xor(mx, 32, 64));
      float l0 = selfsc[bd];                   // self score (incl. bias)
      mx = fmaxf(mx, l0);

      float sum = 0.f;
#pragma unroll
      for (int i = 0; i < 8; ++i) {
        l[i] = __expf(l[i] - mx);
        sum += l[i];
      }
      sum += __shfl_xor(sum, 16, 64);
      sum += __shfl_xor(sum, 32, 64);
      float e0 = __expf(l0 - mx);
      float inv = 1.0f / (sum + e0);

      float w0 = e0 * inv;
      if (w0 < 0.01f) w0 = 0.f;

      float ctxn = 0.f;
#pragma unroll
      for (int mo = 0; mo < 2; ++mo)
#pragma unroll
        for (int r = 0; r < 4; ++r) {
          int k = mo * 16 + quad * 4 + r;
          float w = l[mo * 4 + r] * inv;
          if (w < 0.01f) w = 0.f;
          size_t idx = ((size_t)(b * Kc + k)) * Dc + n_g;
          nbw[idx] = w;
          ctxn += w * bf2f(A[idx]);            // nb_bf value at (b,k,n)
        }
      ctxn += __shfl_xor(ctxn, 16, 64);
      ctxn += __shfl_xor(ctxn, 32, 64);

      if (quad == 0) {
        selfsc[bd] = w0;                       // score -> weight, in place
        float ctx = beta * w0 * bf2f(tc_bf[bd]) + omb * ctxn;
        ctx_bf[bd] = f2bf(ctx);
      }
    }
  }
}

// ---------------------------------------------------------------------------
extern "C" void kernel_launch(void* const* d_in, const int* in_sizes, int n_in,
                              void* d_out, int out_size, void* d_ws,
                              size_t ws_size, hipStream_t stream) {
  const float* target    = (const float*)d_in[0];
  const float* neighbors = (const float*)d_in[1];
  const float* distances = (const float*)d_in[2];
  const float* beta      = (const float*)d_in[3];
  const float* ln_scale  = (const float*)d_in[4];
  const float* ln_bias   = (const float*)d_in[5];
  const float* w_self    = (const float*)d_in[6];
  const float* b_self    = (const float*)d_in[7];
  const float* w_nb      = (const float*)d_in[8];
  const float* b_nb      = (const float*)d_in[9];
  const float* w_red     = (const float*)d_in[10];
  const float* b_red     = (const float*)d_in[11];

  float* out = (float*)d_out;
  float* reduced = out;                          // 4096*128
  float* selfw   = out + (size_t)Bc * Rc;        // 4096*1024 (scores then weights)
  float* nbw     = selfw + (size_t)Bc * Dc;      // 131072*1024 (weights)

  char* ws = (char*)d_ws;
  unsigned short* nb_bf   = (unsigned short*)ws;                      // 268435456 B
  unsigned short* tc_bf   = (unsigned short*)(ws + 268435456);        // 8388608 B
  unsigned short* ctx_bf  = (unsigned short*)(ws + 276824064);        // 8388608 B
  unsigned short* wself_bf = (unsigned short*)(ws + 285212672);       // 2097152 B
  unsigned short* wnb_bf   = (unsigned short*)(ws + 287309824);       // 2097152 B
  unsigned short* wred_bf  = (unsigned short*)(ws + 289406976);       // 262144 B

  // 1. LayerNorm target + neighbors -> bf16
  ln_kernel<<<Bc + MNB, 256, 0, stream>>>(target, neighbors, ln_scale, ln_bias,
                                          tc_bf, nb_bf);
  // 2. weight conversions
  conv_kernel<<<1024, 256, 0, stream>>>(w_self, wself_bf, 262144);
  conv_kernel<<<1024, 256, 0, stream>>>(w_nb, wnb_bf, 262144);
  conv_kernel<<<128, 256, 0, stream>>>(w_red, wred_bf, 32768);
  // 3. self scores: (4096x1024) @ (1024x1024)^T -> selfw region (scores)
  gemm_bf16<0><<<256, 256, 0, stream>>>(tc_bf, wself_bf, b_self, selfw,
                                        Bc, Dc, Dc, 8, 4);
  // 4. fused: neighbor scores GEMM + softmax + threshold + context
  gemm_nb_fused<<<8192, 256, 0, stream>>>(nb_bf, wnb_bf, b_nb, distances, beta,
                                          tc_bf, selfw, nbw, ctx_bf);
  // 5. reduced: (4096x1024) @ (128x1024)^T + bias, leaky -> reduced region
  gemm_bf16<1><<<32, 256, 0, stream>>>(ctx_bf, wred_bf, b_red, reduced,
                                       Bc, Rc, Dc, 1, 4);
}